// Round 5
// baseline (309.985 us; speedup 1.0000x reference)
//
#include <hip/hip_runtime.h>
#include <hip/hip_bf16.h>

#define B_ 4
#define T_ 2048
#define E_ 1024
#define H_ 16
#define DH_ 64
#define QSCALE_ 0.18033688f   // 0.125 * log2(e): QK^T comes out in log2 domain

typedef __attribute__((ext_vector_type(8))) short bf16x8;
typedef __attribute__((ext_vector_type(4))) float f32x4;
typedef unsigned int u32;

__device__ inline ushort f2bf(float f) {
    union { float f; unsigned u; } v; v.f = f;
    unsigned r = (v.u + 0x7fffu + ((v.u >> 16) & 1u)) >> 16;
    return (ushort)r;
}

// pack two f32 -> two bf16 (truncation) in one v_perm_b32: a->low, b->high
__device__ inline u32 pack2bf(float a, float b) {
    union { float f; u32 u; } ua, ub; ua.f = a; ub.f = b;
    return __builtin_amdgcn_perm(ub.u, ua.u, 0x07060302);
}

__device__ inline void gload16(const ushort* g, ushort* l) {
    __builtin_amdgcn_global_load_lds((const __attribute__((address_space(1))) u32*)g,
                                     (__attribute__((address_space(3))) u32*)l, 16, 0, 0);
}

// ---------------- fused f32 -> bf16 convert ----------------
__global__ void cvt_all(const float* __restrict__ x, const float* __restrict__ wq,
                        const float* __restrict__ wp,
                        ushort* __restrict__ xo, ushort* __restrict__ wqo, ushort* __restrict__ wpo)
{
    const int NX = B_ * T_ * E_ / 4;
    const int NW = 3 * E_ * E_ / 4;
    int i = blockIdx.x * 256 + threadIdx.x;
    const float* s; ushort* d; int off;
    if (i < NX)            { s = x;  d = xo;  off = i; }
    else if (i < NX + NW)  { s = wq; d = wqo; off = i - NX; }
    else                   { s = wp; d = wpo; off = i - NX - NW; }
    float4 f = ((const float4*)s)[off];
    ushort4 u;
    u.x = f2bf(f.x); u.y = f2bf(f.y); u.z = f2bf(f.z); u.w = f2bf(f.w);
    ((ushort4*)d)[off] = u;
}

// ---------------- QKV GEMM: 128x128 tile, BK=64, XOR-swizzled LDS (R0-proven) ----------------
__global__ __launch_bounds__(256) void gemm_qkv(
    const ushort* __restrict__ Xb, const ushort* __restrict__ Wb,
    const float* __restrict__ bias,
    ushort* __restrict__ Q, ushort* __restrict__ K, ushort* __restrict__ Vt)
{
    __shared__ ushort As[128 * 64];
    __shared__ ushort Bs[128 * 64];
    const int m0 = blockIdx.x * 128;
    const int n0 = blockIdx.y * 128;
    const int kind = n0 >> 10;           // 0=Q 1=K 2=V (block-uniform)
    const int tid  = threadIdx.x;
    const int wave = tid >> 6, lane = tid & 63;
    const int lrow = lane & 15, quad = lane >> 4;
    const int srow8 = lane >> 3;
    const int scol8 = ((lane & 7) ^ srow8) * 8;   // XOR-swizzled source column

    const ushort* gA = Xb + (size_t)(m0 + wave * 8 + srow8) * 1024 + scol8;
    const ushort* gB = Wb + (size_t)(n0 + wave * 8 + srow8) * 1024 + scol8;

    const int mw = (wave >> 1) * 64, nw = (wave & 1) * 64;
    const int rsw = (lrow & 7);          // row&7 for frag reads

    f32x4 acc[4][4];
#pragma unroll
    for (int i = 0; i < 4; i++)
#pragma unroll
        for (int j = 0; j < 4; j++) acc[i][j] = f32x4{0.f, 0.f, 0.f, 0.f};

    const int b = m0 >> 11;   // batch (block never straddles a 2048 boundary)
    const bool ct = (kind != 2);

    for (int k0 = 0; k0 < 1024; k0 += 64) {
        __syncthreads();
#pragma unroll
        for (int g = 0; g < 4; g++) {
            gload16(gA + (size_t)g * 32 * 1024 + k0, &As[(g * 32 + wave * 8) * 64]);
            gload16(gB + (size_t)g * 32 * 1024 + k0, &Bs[(g * 32 + wave * 8) * 64]);
        }
        __syncthreads();
#pragma unroll
        for (int ks = 0; ks < 2; ks++) {
            const int usw = ((ks * 4 + quad) ^ rsw) * 8;   // swizzled unit offset
            bf16x8 a[4], bfr[4];
#pragma unroll
            for (int i = 0; i < 4; i++)
                a[i] = *(const bf16x8*)&As[(mw + i * 16 + lrow) * 64 + usw];
#pragma unroll
            for (int j = 0; j < 4; j++)
                bfr[j] = *(const bf16x8*)&Bs[(nw + j * 16 + lrow) * 64 + usw];
            if (ct) {
#pragma unroll
                for (int i = 0; i < 4; i++)
#pragma unroll
                    for (int j = 0; j < 4; j++)
                        acc[i][j] = __builtin_amdgcn_mfma_f32_16x16x32_bf16(bfr[j], a[i], acc[i][j], 0, 0, 0);
            } else {
#pragma unroll
                for (int i = 0; i < 4; i++)
#pragma unroll
                    for (int j = 0; j < 4; j++)
                        acc[i][j] = __builtin_amdgcn_mfma_f32_16x16x32_bf16(a[i], bfr[j], acc[i][j], 0, 0, 0);
            }
        }
    }

    if (ct) {
        // C^T: lane holds m = mw+i*16+lrow, n = nw+j*16+quad*4+r -> ushort4 along d
        ushort* dst = (kind == 0) ? Q : K;
        const float scale = (kind == 0) ? QSCALE_ : 1.f;
#pragma unroll
        for (int j = 0; j < 4; j++) {
            int nq = (n0 & 1023) + nw + j * 16 + quad * 4;
            int h = nq >> 6, d = nq & 63;
            float4 bv = *(const float4*)&bias[n0 + nw + j * 16 + quad * 4];
            size_t bh = (size_t)(b * H_ + h);
#pragma unroll
            for (int i = 0; i < 4; i++) {
                int t = (m0 + mw + i * 16 + lrow) & 2047;   // batch-local!
                ushort4 o;
                o.x = f2bf((acc[i][j][0] + bv.x) * scale);
                o.y = f2bf((acc[i][j][1] + bv.y) * scale);
                o.z = f2bf((acc[i][j][2] + bv.z) * scale);
                o.w = f2bf((acc[i][j][3] + bv.w) * scale);
                *(ushort4*)&dst[(bh * T_ + t) * DH_ + d] = o;
            }
        }
    } else {
        // normal: lane holds n = nw+j*16+lrow, t = mw+i*16+quad*4+r -> ushort4 along t
#pragma unroll
        for (int j = 0; j < 4; j++) {
            int nv = (n0 & 1023) + nw + j * 16 + lrow;
            int h = nv >> 6, d = nv & 63;
            float bv = bias[n0 + nw + j * 16 + lrow];
            size_t bh = (size_t)(b * H_ + h);
#pragma unroll
            for (int i = 0; i < 4; i++) {
                int t = (m0 + mw + i * 16 + quad * 4) & 2047;   // batch-local!
                ushort4 o;
                o.x = f2bf(acc[i][j][0] + bv);
                o.y = f2bf(acc[i][j][1] + bv);
                o.z = f2bf(acc[i][j][2] + bv);
                o.w = f2bf(acc[i][j][3] + bv);
                *(ushort4*)&Vt[(bh * DH_ + d) * T_ + t] = o;
            }
        }
    }
}

// ---------------- Flash attention: sequential paired q-tiles, NO K/V LDS staging ----------------
// K/V per head are L2-resident (256 KB each); kb/vb MFMA fragments are loaded
// directly from global (16 B/lane, 16 rows x 64 B chunks -> coalesced).
// Removes Ks/Vt LDS, all kt-loop barriers (Ps is wave-private: writer wave ==
// reader wave), and the prefetch register set. Same bf16 bits, same MFMA and
// summation order as the R0-proven version -> identical numerics.
#define LDT_ 76

__global__ __launch_bounds__(256) void flash_attn(
    const ushort* __restrict__ Q, const ushort* __restrict__ K,
    const ushort* __restrict__ Vg,   // [bh][DH][T]
    ushort* __restrict__ O)
{
    __shared__ ushort Ps[128 * LDT_];   // P staging; doubles as Q staging

    const int qtA = 15 - blockIdx.x;     // long tile
    const int qtB = blockIdx.x;          // short tile
    const int bh = blockIdx.y;
    const int tid  = threadIdx.x;
    const int wave = tid >> 6, lane = tid & 63;
    const int lrow = lane & 15, quad = lane >> 4;

    const ushort* Qbh = Q  + (size_t)bh * T_ * DH_;
    const ushort* Kbh = K  + (size_t)bh * T_ * DH_;
    const ushort* Vbh = Vg + (size_t)bh * DH_ * T_;
    const int b_ = bh >> 4, h_ = bh & 15;

    auto stageQ = [&](int qt, bf16x8 qa[2][2]) {
        int qr = tid >> 1, qc = (tid & 1) * 32;
        const ushort* src = &Qbh[(size_t)(qt * 128 + qr) * DH_ + qc];
#pragma unroll
        for (int i = 0; i < 4; i++)
            *(int4*)&Ps[qr * LDT_ + qc + 8 * i] = *(const int4*)&src[8 * i];
        __syncthreads();
#pragma unroll
        for (int s = 0; s < 2; s++)
#pragma unroll
            for (int h = 0; h < 2; h++)
                qa[s][h] = *(const bf16x8*)&Ps[(s * 64 + wave * 16 + lrow) * LDT_ + h * 32 + quad * 8];
    };

    auto run = [&](const bf16x8 (&qa)[2][2], int qt) {
        const int lastkt = 2 * qt + 1;

        float ls[2] = {0.f, 0.f};
        f32x4 accO[2][4];
#pragma unroll
        for (int s = 0; s < 2; s++)
#pragma unroll
            for (int j = 0; j < 4; j++) accO[s][j] = f32x4{0.f, 0.f, 0.f, 0.f};

        const ushort* Kl = Kbh + (size_t)lrow * DH_ + quad * 8;   // row base, 16B chunk
        const ushort* Vl = Vbh + (size_t)lrow * T_ + quad * 8;

        for (int kt = 0; kt <= lastkt; ++kt) {
            // direct global fragment loads (no LDS, no barriers)
            bf16x8 kb0[4], kb1[4], vb0[4], vb1[4];
#pragma unroll
            for (int j = 0; j < 4; j++) {
                const ushort* kp = Kl + (size_t)(kt * 64 + j * 16) * DH_;
                kb0[j] = *(const bf16x8*)kp;
                kb1[j] = *(const bf16x8*)(kp + 32);
                const ushort* vp = Vl + (size_t)(j * 16) * T_ + kt * 64;
                vb0[j] = *(const bf16x8*)vp;
                vb1[j] = *(const bf16x8*)(vp + 32);
            }

            const bool do0 = (kt != lastkt);
#pragma unroll
            for (int s = 0; s < 2; s++) {
                if (s == 0 && !do0) continue;
                f32x4 st[4];
#pragma unroll
                for (int j = 0; j < 4; j++) {
                    f32x4 sj = f32x4{0.f, 0.f, 0.f, 0.f};
                    sj = __builtin_amdgcn_mfma_f32_16x16x32_bf16(kb0[j], qa[s][0], sj, 0, 0, 0);
                    sj = __builtin_amdgcn_mfma_f32_16x16x32_bf16(kb1[j], qa[s][1], sj, 0, 0, 0);
                    st[j] = sj;
                }
                if (kt == 2 * qt + s) {
                    const int qrow = qt * 128 + s * 64 + wave * 16 + lrow;
                    const int keyb = kt * 64 + quad * 4;
#pragma unroll
                    for (int j = 0; j < 4; j++)
#pragma unroll
                        for (int r = 0; r < 4; r++)
                            if (keyb + j * 16 + r > qrow) st[j][r] = -1e30f;
                }
                float lp = 0.f;
#pragma unroll
                for (int j = 0; j < 4; j++)
#pragma unroll
                    for (int r = 0; r < 4; r++) {
                        float p = __builtin_amdgcn_exp2f(st[j][r]);
                        st[j][r] = p;
                        lp += p;
                    }
                ls[s] += lp;
                ushort* prow = &Ps[(s * 64 + wave * 16 + lrow) * LDT_ + quad * 4];
#pragma unroll
                for (int j = 0; j < 4; j++) {
                    *(u32*)&prow[j * 16]     = pack2bf(st[j][0], st[j][1]);
                    *(u32*)&prow[j * 16 + 2] = pack2bf(st[j][2], st[j][3]);
                }
            }

#pragma unroll
            for (int s = 0; s < 2; s++) {
                if (s == 0 && !do0) continue;
                bf16x8 pa0 = *(const bf16x8*)&Ps[(s * 64 + wave * 16 + lrow) * LDT_ + quad * 8];
                bf16x8 pa1 = *(const bf16x8*)&Ps[(s * 64 + wave * 16 + lrow) * LDT_ + 32 + quad * 8];
#pragma unroll
                for (int jd = 0; jd < 4; jd++) {
                    accO[s][jd] = __builtin_amdgcn_mfma_f32_16x16x32_bf16(pa0, vb0[jd], accO[s][jd], 0, 0, 0);
                    accO[s][jd] = __builtin_amdgcn_mfma_f32_16x16x32_bf16(pa1, vb1[jd], accO[s][jd], 0, 0, 0);
                }
            }
        }

#pragma unroll
        for (int s = 0; s < 2; s++) {
            ls[s] += __shfl_xor(ls[s], 16, 64);
            ls[s] += __shfl_xor(ls[s], 32, 64);
        }
#pragma unroll
        for (int s = 0; s < 2; s++) {
#pragma unroll
            for (int r = 0; r < 4; r++) {
                float lv = __shfl(ls[s], quad * 4 + r, 64);
                float inv = 1.f / lv;
                int t = qt * 128 + s * 64 + wave * 16 + quad * 4 + r;
#pragma unroll
                for (int jd = 0; jd < 4; jd++) {
                    int d = jd * 16 + lrow;
                    O[((size_t)(b_ * T_ + t)) * E_ + h_ * DH_ + d] = f2bf(accO[s][jd][r] * inv);
                }
            }
        }
    };

    // A first; stage B's Q only after A finishes (keeps qaB's registers out of
    // run A -> lower peak VGPR). Barrier protects Ps reuse across waves.
    bf16x8 qaA[2][2];
    stageQ(qtA, qaA);
    run(qaA, qtA);
    __syncthreads();
    bf16x8 qaB[2][2];
    stageQ(qtB, qaB);
    run(qaB, qtB);
}

// ---------------- proj GEMM: 128x128 tile, BK=64, XOR-swizzled, C^T stores (R0-proven) ----------------
__global__ __launch_bounds__(256) void gemm_proj(
    const ushort* __restrict__ Ob, const ushort* __restrict__ Wb,
    const float* __restrict__ bias, float* __restrict__ out)
{
    __shared__ ushort As[128 * 64];
    __shared__ ushort Bs[128 * 64];
    const int m0 = blockIdx.x * 128;
    const int n0 = blockIdx.y * 128;
    const int tid  = threadIdx.x;
    const int wave = tid >> 6, lane = tid & 63;
    const int lrow = lane & 15, quad = lane >> 4;
    const int srow8 = lane >> 3;
    const int scol8 = ((lane & 7) ^ srow8) * 8;

    const ushort* gA = Ob + (size_t)(m0 + wave * 8 + srow8) * 1024 + scol8;
    const ushort* gB = Wb + (size_t)(n0 + wave * 8 + srow8) * 1024 + scol8;

    const int mw = (wave >> 1) * 64, nw = (wave & 1) * 64;
    const int rsw = (lrow & 7);

    f32x4 acc[4][4];
#pragma unroll
    for (int i = 0; i < 4; i++)
#pragma unroll
        for (int j = 0; j < 4; j++) acc[i][j] = f32x4{0.f, 0.f, 0.f, 0.f};

    for (int k0 = 0; k0 < 1024; k0 += 64) {
        __syncthreads();
#pragma unroll
        for (int g = 0; g < 4; g++) {
            gload16(gA + (size_t)g * 32 * 1024 + k0, &As[(g * 32 + wave * 8) * 64]);
            gload16(gB + (size_t)g * 32 * 1024 + k0, &Bs[(g * 32 + wave * 8) * 64]);
        }
        __syncthreads();
#pragma unroll
        for (int ks = 0; ks < 2; ks++) {
            const int usw = ((ks * 4 + quad) ^ rsw) * 8;
            bf16x8 a[4], bfr[4];
#pragma unroll
            for (int i = 0; i < 4; i++)
                a[i] = *(const bf16x8*)&As[(mw + i * 16 + lrow) * 64 + usw];
#pragma unroll
            for (int j = 0; j < 4; j++)
                bfr[j] = *(const bf16x8*)&Bs[(nw + j * 16 + lrow) * 64 + usw];
#pragma unroll
            for (int i = 0; i < 4; i++)
#pragma unroll
                for (int j = 0; j < 4; j++)
                    acc[i][j] = __builtin_amdgcn_mfma_f32_16x16x32_bf16(bfr[j], a[i], acc[i][j], 0, 0, 0);
        }
    }

#pragma unroll
    for (int j = 0; j < 4; j++) {
        int n = n0 + nw + j * 16 + quad * 4;
        float4 bv = *(const float4*)&bias[n];
#pragma unroll
        for (int i = 0; i < 4; i++) {
            int m = m0 + mw + i * 16 + lrow;
            float4 o;
            o.x = acc[i][j][0] + bv.x;
            o.y = acc[i][j][1] + bv.y;
            o.z = acc[i][j][2] + bv.z;
            o.w = acc[i][j][3] + bv.w;
            *(float4*)&out[(size_t)m * 1024 + n] = o;
        }
    }
}

extern "C" void kernel_launch(void* const* d_in, const int* in_sizes, int n_in,
                              void* d_out, int out_size, void* d_ws, size_t ws_size,
                              hipStream_t stream) {
    const float* x      = (const float*)d_in[0];
    const float* w_qkv  = (const float*)d_in[1];
    const float* b_qkv  = (const float*)d_in[2];
    const float* w_proj = (const float*)d_in[3];
    const float* b_proj = (const float*)d_in[4];
    float* out = (float*)d_out;

    char* ws = (char*)d_ws;
    ushort* Xb     = (ushort*)ws; ws += (size_t)B_ * T_ * E_ * 2;
    ushort* Wqkvb  = (ushort*)ws; ws += (size_t)3 * E_ * E_ * 2;
    ushort* Wprojb = (ushort*)ws; ws += (size_t)E_ * E_ * 2;
    ushort* Qb     = (ushort*)ws; ws += (size_t)B_ * H_ * T_ * DH_ * 2;
    ushort* Kb     = (ushort*)ws; ws += (size_t)B_ * H_ * T_ * DH_ * 2;
    ushort* Vtb    = (ushort*)ws; ws += (size_t)B_ * H_ * T_ * DH_ * 2;
    ushort* Ob     = (ushort*)ws; ws += (size_t)B_ * T_ * E_ * 2;

    int ntot = (B_ * T_ * E_ + 3 * E_ * E_ + E_ * E_) / 4;
    cvt_all<<<ntot / 256, 256, 0, stream>>>(x, w_qkv, w_proj, Xb, Wqkvb, Wprojb);

    gemm_qkv<<<dim3(64, 24), 256, 0, stream>>>(Xb, Wqkvb, b_qkv, Qb, Kb, Vtb);
    flash_attn<<<dim3(8, 64), 256, 0, stream>>>(Qb, Kb, Vtb, Ob);
    gemm_proj<<<dim3(64, 8), 256, 0, stream>>>(Ob, Wprojb, b_proj, out);
}

// Round 6
// 238.353 us; speedup vs baseline: 1.3005x; 1.3005x over previous
//
#include <hip/hip_runtime.h>
#include <hip/hip_bf16.h>

#define B_ 4
#define T_ 2048
#define E_ 1024
#define H_ 16
#define DH_ 64
#define QSCALE_ 0.18033688f   // 0.125 * log2(e): QK^T comes out in log2 domain

typedef __attribute__((ext_vector_type(8))) short bf16x8;
typedef __attribute__((ext_vector_type(4))) float f32x4;
typedef unsigned int u32;

__device__ inline ushort f2bf(float f) {
    union { float f; unsigned u; } v; v.f = f;
    unsigned r = (v.u + 0x7fffu + ((v.u >> 16) & 1u)) >> 16;
    return (ushort)r;
}

// pack two f32 -> two bf16 (truncation) in one v_perm_b32: a->low, b->high
__device__ inline u32 pack2bf(float a, float b) {
    union { float f; u32 u; } ua, ub; ua.f = a; ub.f = b;
    return __builtin_amdgcn_perm(ub.u, ua.u, 0x07060302);
}

__device__ inline void gload16(const ushort* g, ushort* l) {
    __builtin_amdgcn_global_load_lds((const __attribute__((address_space(1))) u32*)g,
                                     (__attribute__((address_space(3))) u32*)l, 16, 0, 0);
}

// ---------------- fused f32 -> bf16 convert ----------------
__global__ void cvt_all(const float* __restrict__ x, const float* __restrict__ wq,
                        const float* __restrict__ wp,
                        ushort* __restrict__ xo, ushort* __restrict__ wqo, ushort* __restrict__ wpo)
{
    const int NX = B_ * T_ * E_ / 4;
    const int NW = 3 * E_ * E_ / 4;
    int i = blockIdx.x * 256 + threadIdx.x;
    const float* s; ushort* d; int off;
    if (i < NX)            { s = x;  d = xo;  off = i; }
    else if (i < NX + NW)  { s = wq; d = wqo; off = i - NX; }
    else                   { s = wp; d = wpo; off = i - NX - NW; }
    float4 f = ((const float4*)s)[off];
    ushort4 u;
    u.x = f2bf(f.x); u.y = f2bf(f.y); u.z = f2bf(f.z); u.w = f2bf(f.w);
    ((ushort4*)d)[off] = u;
}

// ---------------- QKV GEMM: 128x128 tile, BK=64, XOR-swizzled LDS (R0-proven) ----------------
__global__ __launch_bounds__(256) void gemm_qkv(
    const ushort* __restrict__ Xb, const ushort* __restrict__ Wb,
    const float* __restrict__ bias,
    ushort* __restrict__ Q, ushort* __restrict__ K, ushort* __restrict__ Vt)
{
    __shared__ ushort As[128 * 64];
    __shared__ ushort Bs[128 * 64];
    const int m0 = blockIdx.x * 128;
    const int n0 = blockIdx.y * 128;
    const int kind = n0 >> 10;           // 0=Q 1=K 2=V (block-uniform)
    const int tid  = threadIdx.x;
    const int wave = tid >> 6, lane = tid & 63;
    const int lrow = lane & 15, quad = lane >> 4;
    const int srow8 = lane >> 3;
    const int scol8 = ((lane & 7) ^ srow8) * 8;   // XOR-swizzled source column

    const ushort* gA = Xb + (size_t)(m0 + wave * 8 + srow8) * 1024 + scol8;
    const ushort* gB = Wb + (size_t)(n0 + wave * 8 + srow8) * 1024 + scol8;

    const int mw = (wave >> 1) * 64, nw = (wave & 1) * 64;
    const int rsw = (lrow & 7);          // row&7 for frag reads

    f32x4 acc[4][4];
#pragma unroll
    for (int i = 0; i < 4; i++)
#pragma unroll
        for (int j = 0; j < 4; j++) acc[i][j] = f32x4{0.f, 0.f, 0.f, 0.f};

    const int b = m0 >> 11;   // batch (block never straddles a 2048 boundary)
    const bool ct = (kind != 2);

    for (int k0 = 0; k0 < 1024; k0 += 64) {
        __syncthreads();
#pragma unroll
        for (int g = 0; g < 4; g++) {
            gload16(gA + (size_t)g * 32 * 1024 + k0, &As[(g * 32 + wave * 8) * 64]);
            gload16(gB + (size_t)g * 32 * 1024 + k0, &Bs[(g * 32 + wave * 8) * 64]);
        }
        __syncthreads();
#pragma unroll
        for (int ks = 0; ks < 2; ks++) {
            const int usw = ((ks * 4 + quad) ^ rsw) * 8;   // swizzled unit offset
            bf16x8 a[4], bfr[4];
#pragma unroll
            for (int i = 0; i < 4; i++)
                a[i] = *(const bf16x8*)&As[(mw + i * 16 + lrow) * 64 + usw];
#pragma unroll
            for (int j = 0; j < 4; j++)
                bfr[j] = *(const bf16x8*)&Bs[(nw + j * 16 + lrow) * 64 + usw];
            if (ct) {
#pragma unroll
                for (int i = 0; i < 4; i++)
#pragma unroll
                    for (int j = 0; j < 4; j++)
                        acc[i][j] = __builtin_amdgcn_mfma_f32_16x16x32_bf16(bfr[j], a[i], acc[i][j], 0, 0, 0);
            } else {
#pragma unroll
                for (int i = 0; i < 4; i++)
#pragma unroll
                    for (int j = 0; j < 4; j++)
                        acc[i][j] = __builtin_amdgcn_mfma_f32_16x16x32_bf16(a[i], bfr[j], acc[i][j], 0, 0, 0);
            }
        }
    }

    if (ct) {
        // C^T: lane holds m = mw+i*16+lrow, n = nw+j*16+quad*4+r -> ushort4 along d
        ushort* dst = (kind == 0) ? Q : K;
        const float scale = (kind == 0) ? QSCALE_ : 1.f;
#pragma unroll
        for (int j = 0; j < 4; j++) {
            int nq = (n0 & 1023) + nw + j * 16 + quad * 4;
            int h = nq >> 6, d = nq & 63;
            float4 bv = *(const float4*)&bias[n0 + nw + j * 16 + quad * 4];
            size_t bh = (size_t)(b * H_ + h);
#pragma unroll
            for (int i = 0; i < 4; i++) {
                int t = (m0 + mw + i * 16 + lrow) & 2047;   // batch-local!
                ushort4 o;
                o.x = f2bf((acc[i][j][0] + bv.x) * scale);
                o.y = f2bf((acc[i][j][1] + bv.y) * scale);
                o.z = f2bf((acc[i][j][2] + bv.z) * scale);
                o.w = f2bf((acc[i][j][3] + bv.w) * scale);
                *(ushort4*)&dst[(bh * T_ + t) * DH_ + d] = o;
            }
        }
    } else {
        // normal: lane holds n = nw+j*16+lrow, t = mw+i*16+quad*4+r -> ushort4 along t
#pragma unroll
        for (int j = 0; j < 4; j++) {
            int nv = (n0 & 1023) + nw + j * 16 + lrow;
            int h = nv >> 6, d = nv & 63;
            float bv = bias[n0 + nw + j * 16 + lrow];
            size_t bh = (size_t)(b * H_ + h);
#pragma unroll
            for (int i = 0; i < 4; i++) {
                int t = (m0 + mw + i * 16 + quad * 4) & 2047;   // batch-local!
                ushort4 o;
                o.x = f2bf(acc[i][j][0] + bv);
                o.y = f2bf(acc[i][j][1] + bv);
                o.z = f2bf(acc[i][j][2] + bv);
                o.w = f2bf(acc[i][j][3] + bv);
                *(ushort4*)&Vt[(bh * DH_ + d) * T_ + t] = o;
            }
        }
    }
}

// ---------------- Flash attention: paired q-tiles (R0-proven) + XCD-locality remap ----------------
// Remap (bijective): d = bx + 8*by; bh = (d&7) + 8*(d>>6); qx = (d>>3)&7.
// With round-robin dispatch (xcd = d%8), all 8 q-tile blocks of one head land
// on ONE XCD, and each XCD's working set = 8 heads x 512KB K/V = 4MB = L2.
// If dispatch order differs, this is just another valid permutation (safe).
#define LDT_ 76

__global__ __launch_bounds__(256) void flash_attn(
    const ushort* __restrict__ Q, const ushort* __restrict__ K,
    const ushort* __restrict__ Vg,   // [bh][DH][T]
    ushort* __restrict__ O)
{
    __shared__ ushort Ks[64 * LDT_];
    __shared__ ushort Vt[64 * LDT_];
    __shared__ ushort Ps[128 * LDT_];   // doubles as Q staging

    const int d__ = blockIdx.x + 8 * blockIdx.y;
    const int bh  = (d__ & 7) + 8 * (d__ >> 6);
    const int qx  = (d__ >> 3) & 7;
    const int qtA = 15 - qx;             // long tile
    const int qtB = qx;                  // short tile
    const int tid  = threadIdx.x;
    const int wave = tid >> 6, lane = tid & 63;
    const int lrow = lane & 15, quad = lane >> 4;
    const int sr = tid >> 2, sc = (tid & 3) * 16;   // K/V staging coords

    const ushort* Qbh = Q  + (size_t)bh * T_ * DH_;
    const ushort* Kbh = K  + (size_t)bh * T_ * DH_;
    const ushort* Vbh = Vg + (size_t)bh * DH_ * T_;
    const int b_ = bh >> 4, h_ = bh & 15;

    auto stageQ = [&](int qt, bf16x8 qa[2][2]) {
        int qr = tid >> 1, qc = (tid & 1) * 32;
        const ushort* src = &Qbh[(size_t)(qt * 128 + qr) * DH_ + qc];
#pragma unroll
        for (int i = 0; i < 4; i++)
            *(int4*)&Ps[qr * LDT_ + qc + 8 * i] = *(const int4*)&src[8 * i];
        __syncthreads();
#pragma unroll
        for (int s = 0; s < 2; s++)
#pragma unroll
            for (int h = 0; h < 2; h++)
                qa[s][h] = *(const bf16x8*)&Ps[(s * 64 + wave * 16 + lrow) * LDT_ + h * 32 + quad * 8];
    };

    bf16x8 qaA[2][2], qaB[2][2];
    stageQ(qtA, qaA);
    __syncthreads();
    stageQ(qtB, qaB);

    auto run = [&](const bf16x8 (&qa)[2][2], int qt) {
        const int lastkt = 2 * qt + 1;

        int4 kr0 = *(const int4*)&Kbh[(size_t)sr * DH_ + sc];
        int4 kr1 = *(const int4*)&Kbh[(size_t)sr * DH_ + sc + 8];
        int4 vr0 = *(const int4*)&Vbh[(size_t)sr * T_ + sc];
        int4 vr1 = *(const int4*)&Vbh[(size_t)sr * T_ + sc + 8];

        float ls[2] = {0.f, 0.f};
        f32x4 accO[2][4];
#pragma unroll
        for (int s = 0; s < 2; s++)
#pragma unroll
            for (int j = 0; j < 4; j++) accO[s][j] = f32x4{0.f, 0.f, 0.f, 0.f};

        for (int kt = 0; kt <= lastkt; ++kt) {
            __syncthreads();
            *(int4*)&Ks[sr * LDT_ + sc]     = kr0;
            *(int4*)&Ks[sr * LDT_ + sc + 8] = kr1;
            *(int4*)&Vt[sr * LDT_ + sc]     = vr0;
            *(int4*)&Vt[sr * LDT_ + sc + 8] = vr1;
            __syncthreads();
            if (kt < lastkt) {
                kr0 = *(const int4*)&Kbh[(size_t)((kt + 1) * 64 + sr) * DH_ + sc];
                kr1 = *(const int4*)&Kbh[(size_t)((kt + 1) * 64 + sr) * DH_ + sc + 8];
                vr0 = *(const int4*)&Vbh[(size_t)sr * T_ + (kt + 1) * 64 + sc];
                vr1 = *(const int4*)&Vbh[(size_t)sr * T_ + (kt + 1) * 64 + sc + 8];
            }

            bf16x8 kb0[4], kb1[4];
#pragma unroll
            for (int j = 0; j < 4; j++) {
                kb0[j] = *(const bf16x8*)&Ks[(j * 16 + lrow) * LDT_ + quad * 8];
                kb1[j] = *(const bf16x8*)&Ks[(j * 16 + lrow) * LDT_ + 32 + quad * 8];
            }

            const bool do0 = (kt != lastkt);
#pragma unroll
            for (int s = 0; s < 2; s++) {
                if (s == 0 && !do0) continue;
                f32x4 st[4];
#pragma unroll
                for (int j = 0; j < 4; j++) {
                    f32x4 sj = f32x4{0.f, 0.f, 0.f, 0.f};
                    sj = __builtin_amdgcn_mfma_f32_16x16x32_bf16(kb0[j], qa[s][0], sj, 0, 0, 0);
                    sj = __builtin_amdgcn_mfma_f32_16x16x32_bf16(kb1[j], qa[s][1], sj, 0, 0, 0);
                    st[j] = sj;
                }
                if (kt == 2 * qt + s) {
                    const int qrow = qt * 128 + s * 64 + wave * 16 + lrow;
                    const int keyb = kt * 64 + quad * 4;
#pragma unroll
                    for (int j = 0; j < 4; j++)
#pragma unroll
                        for (int r = 0; r < 4; r++)
                            if (keyb + j * 16 + r > qrow) st[j][r] = -1e30f;
                }
                float lp = 0.f;
#pragma unroll
                for (int j = 0; j < 4; j++)
#pragma unroll
                    for (int r = 0; r < 4; r++) {
                        float p = __builtin_amdgcn_exp2f(st[j][r]);
                        st[j][r] = p;
                        lp += p;
                    }
                ls[s] += lp;
                ushort* prow = &Ps[(s * 64 + wave * 16 + lrow) * LDT_ + quad * 4];
#pragma unroll
                for (int j = 0; j < 4; j++) {
                    *(u32*)&prow[j * 16]     = pack2bf(st[j][0], st[j][1]);
                    *(u32*)&prow[j * 16 + 2] = pack2bf(st[j][2], st[j][3]);
                }
            }

            bf16x8 vb0[4], vb1[4];
#pragma unroll
            for (int j = 0; j < 4; j++) {
                vb0[j] = *(const bf16x8*)&Vt[(j * 16 + lrow) * LDT_ + quad * 8];
                vb1[j] = *(const bf16x8*)&Vt[(j * 16 + lrow) * LDT_ + 32 + quad * 8];
            }
#pragma unroll
            for (int s = 0; s < 2; s++) {
                if (s == 0 && !do0) continue;
                bf16x8 pa0 = *(const bf16x8*)&Ps[(s * 64 + wave * 16 + lrow) * LDT_ + quad * 8];
                bf16x8 pa1 = *(const bf16x8*)&Ps[(s * 64 + wave * 16 + lrow) * LDT_ + 32 + quad * 8];
#pragma unroll
                for (int jd = 0; jd < 4; jd++) {
                    accO[s][jd] = __builtin_amdgcn_mfma_f32_16x16x32_bf16(pa0, vb0[jd], accO[s][jd], 0, 0, 0);
                    accO[s][jd] = __builtin_amdgcn_mfma_f32_16x16x32_bf16(pa1, vb1[jd], accO[s][jd], 0, 0, 0);
                }
            }
        }

#pragma unroll
        for (int s = 0; s < 2; s++) {
            ls[s] += __shfl_xor(ls[s], 16, 64);
            ls[s] += __shfl_xor(ls[s], 32, 64);
        }
#pragma unroll
        for (int s = 0; s < 2; s++) {
#pragma unroll
            for (int r = 0; r < 4; r++) {
                float lv = __shfl(ls[s], quad * 4 + r, 64);
                float inv = 1.f / lv;
                int t = qt * 128 + s * 64 + wave * 16 + quad * 4 + r;
#pragma unroll
                for (int jd = 0; jd < 4; jd++) {
                    int d = jd * 16 + lrow;
                    O[((size_t)(b_ * T_ + t)) * E_ + h_ * DH_ + d] = f2bf(accO[s][jd][r] * inv);
                }
            }
        }
    };

    run(qaA, qtA);
    run(qaB, qtB);
}

// ---------------- proj GEMM: 128x128 tile, BK=64, XOR-swizzled, C^T stores (R0-proven) ----------------
__global__ __launch_bounds__(256) void gemm_proj(
    const ushort* __restrict__ Ob, const ushort* __restrict__ Wb,
    const float* __restrict__ bias, float* __restrict__ out)
{
    __shared__ ushort As[128 * 64];
    __shared__ ushort Bs[128 * 64];
    const int m0 = blockIdx.x * 128;
    const int n0 = blockIdx.y * 128;
    const int tid  = threadIdx.x;
    const int wave = tid >> 6, lane = tid & 63;
    const int lrow = lane & 15, quad = lane >> 4;
    const int srow8 = lane >> 3;
    const int scol8 = ((lane & 7) ^ srow8) * 8;

    const ushort* gA = Ob + (size_t)(m0 + wave * 8 + srow8) * 1024 + scol8;
    const ushort* gB = Wb + (size_t)(n0 + wave * 8 + srow8) * 1024 + scol8;

    const int mw = (wave >> 1) * 64, nw = (wave & 1) * 64;
    const int rsw = (lrow & 7);

    f32x4 acc[4][4];
#pragma unroll
    for (int i = 0; i < 4; i++)
#pragma unroll
        for (int j = 0; j < 4; j++) acc[i][j] = f32x4{0.f, 0.f, 0.f, 0.f};

    for (int k0 = 0; k0 < 1024; k0 += 64) {
        __syncthreads();
#pragma unroll
        for (int g = 0; g < 4; g++) {
            gload16(gA + (size_t)g * 32 * 1024 + k0, &As[(g * 32 + wave * 8) * 64]);
            gload16(gB + (size_t)g * 32 * 1024 + k0, &Bs[(g * 32 + wave * 8) * 64]);
        }
        __syncthreads();
#pragma unroll
        for (int ks = 0; ks < 2; ks++) {
            const int usw = ((ks * 4 + quad) ^ rsw) * 8;
            bf16x8 a[4], bfr[4];
#pragma unroll
            for (int i = 0; i < 4; i++)
                a[i] = *(const bf16x8*)&As[(mw + i * 16 + lrow) * 64 + usw];
#pragma unroll
            for (int j = 0; j < 4; j++)
                bfr[j] = *(const bf16x8*)&Bs[(nw + j * 16 + lrow) * 64 + usw];
#pragma unroll
            for (int i = 0; i < 4; i++)
#pragma unroll
                for (int j = 0; j < 4; j++)
                    acc[i][j] = __builtin_amdgcn_mfma_f32_16x16x32_bf16(bfr[j], a[i], acc[i][j], 0, 0, 0);
        }
    }

#pragma unroll
    for (int j = 0; j < 4; j++) {
        int n = n0 + nw + j * 16 + quad * 4;
        float4 bv = *(const float4*)&bias[n];
#pragma unroll
        for (int i = 0; i < 4; i++) {
            int m = m0 + mw + i * 16 + lrow;
            float4 o;
            o.x = acc[i][j][0] + bv.x;
            o.y = acc[i][j][1] + bv.y;
            o.z = acc[i][j][2] + bv.z;
            o.w = acc[i][j][3] + bv.w;
            *(float4*)&out[(size_t)m * 1024 + n] = o;
        }
    }
}

extern "C" void kernel_launch(void* const* d_in, const int* in_sizes, int n_in,
                              void* d_out, int out_size, void* d_ws, size_t ws_size,
                              hipStream_t stream) {
    const float* x      = (const float*)d_in[0];
    const float* w_qkv  = (const float*)d_in[1];
    const float* b_qkv  = (const float*)d_in[2];
    const float* w_proj = (const float*)d_in[3];
    const float* b_proj = (const float*)d_in[4];
    float* out = (float*)d_out;

    char* ws = (char*)d_ws;
    ushort* Xb     = (ushort*)ws; ws += (size_t)B_ * T_ * E_ * 2;
    ushort* Wqkvb  = (ushort*)ws; ws += (size_t)3 * E_ * E_ * 2;
    ushort* Wprojb = (ushort*)ws; ws += (size_t)E_ * E_ * 2;
    ushort* Qb     = (ushort*)ws; ws += (size_t)B_ * H_ * T_ * DH_ * 2;
    ushort* Kb     = (ushort*)ws; ws += (size_t)B_ * H_ * T_ * DH_ * 2;
    ushort* Vtb    = (ushort*)ws; ws += (size_t)B_ * H_ * T_ * DH_ * 2;
    ushort* Ob     = (ushort*)ws; ws += (size_t)B_ * T_ * E_ * 2;

    int ntot = (B_ * T_ * E_ + 3 * E_ * E_ + E_ * E_) / 4;
    cvt_all<<<ntot / 256, 256, 0, stream>>>(x, w_qkv, w_proj, Xb, Wqkvb, Wprojb);

    gemm_qkv<<<dim3(64, 24), 256, 0, stream>>>(Xb, Wqkvb, b_qkv, Qb, Kb, Vtb);
    flash_attn<<<dim3(8, 64), 256, 0, stream>>>(Qb, Kb, Vtb, Ob);
    gemm_proj<<<dim3(64, 8), 256, 0, stream>>>(Ob, Wprojb, b_proj, out);
}